// Round 10
// baseline (285.952 us; speedup 1.0000x reference)
//
#include <hip/hip_runtime.h>
#include <hip/hip_bf16.h>

typedef _Float16 v8h __attribute__((ext_vector_type(8)));
typedef _Float16 v4h __attribute__((ext_vector_type(4)));
typedef _Float16 v2h __attribute__((ext_vector_type(2)));
typedef float    v4f __attribute__((ext_vector_type(4)));

#define NTOT  16384
#define NN    70
#define STEPS 5
#define TPB   64                     // ONE wave per block
#define GPW   2                      // TWO independent graphs per wave (ILP)
#define NBLK  (NTOT/GPW)             // 8192 blocks
// r0-r7 invariant: ~7 wave-slots/CU active in EVERY config; only per-wave
// wall W ever moved perf. W is ~70% latency stall -> fill with a 2nd graph's
// instructions in the SAME wave. r8 validated the structure but the compiler
// squeezed to the 128-VGPR tier and SPILLED (WRITE 4.9->37.7MB). This round:
// pin the register ceiling with amdgpu_waves_per_eu(2,2) -> full 256 budget.
#define CATN  40                     // cat node stride (r6-validated; CATN 32
                                     // unswizzled doubles conflicts -- r7)
#define CATH  3208                   // 80 nodes * 40 + pad
#define USTR  232                    // U col stride (halves): 116 dw == 20 mod 32
#define UH    (10*USTR)              // 10 real cols; phantom-col B-frag reads
                                     // (c>=10) land in same graph's cat: finite,
                                     // D rows 10..15 discarded (r2/r3/r6-validated)

// epilogue weights (fp32, global scalar loads)
#define PWO1 0                       // 10 rows x 12: [Wo1[s][0..9], ann_coef, bo1[s]]
#define PWO2 120
#define PBO2 130
#define NWP  132

// fp16 fragment images (built by prep):
//  [0..1023]     P1 B-frags Wstack, 2 tiles:  nt*512 + lane*8 + j
//  [1024..2047]  P3 A-frags Wr | Wz:          mt*512 + lane*8 + j
//  [2048..2559]  P3 A-frag  Wh:               lane*8 + j
//  [2560..20479] adjacency frags:             2560 + (mt*7+kt)*512 + lane*8 + j
//  NOTE: A-frag image of M == B-frag image of M^T for 16x16x32 (identical
//  (lane,j)->(row/col,k) map), so adjacency images serve as swapped-P2's B operand.
#define OFR  1024
#define OFZ  1536
#define OFH  2048
#define OFA  2560
#define NWF  20480
#define PREPB 40

__device__ __align__(16) float    g_w[NWP];
__device__ __align__(16) _Float16 g_wf[NWF];
__device__ int g_flag;

__device__ __forceinline__ float fast_sigmoid(float x) {
    return __builtin_amdgcn_rcpf(1.0f + __expf(-x));
}
__device__ __forceinline__ float fast_tanh(float x) {
    float ax = fabsf(x);
    float e  = __expf(-2.0f * ax);
    float t  = (1.0f - e) * __builtin_amdgcn_rcpf(1.0f + e);
    return copysignf(t, x);
}

struct __align__(16) Smem {
    _Float16 U[UH];      // 4640 B: U[col=s][k=e*72+node]
    _Float16 cat[CATH];  // 6416 B: cat[node][k]; k0..9=a_in, 16..25=prop, 26=1
};
// 11056 B per graph; block = 2 graphs = 22112 B -> alloc 22528 -> 7 blocks/CU
// (= the observed active wave-slot count) holding 14 graphs in flight.

// ---- prep: probe dtype; build epilogue weights + all fp16 fragment images ----
__global__ void prep_kernel(const void* annv, const void* Av,
    const void* winv, const void* binv, const void* wrv, const void* brv,
    const void* wzv, const void* bzv, const void* whv, const void* bhv,
    const void* wo1v, const void* bo1v, const void* wo2v, const void* bo2v)
{
    __shared__ int sflag;
    if (threadIdx.x == 0) {
        const unsigned short* u = (const unsigned short*)annv;
        int good = 0;
        for (int k = 0; k < 128; ++k) {
            unsigned short bb = u[k];
            int ex = (bb >> 7) & 0xFF;
            if (bb == 0 || (ex >= 101 && ex <= 131)) ++good;
        }
        sflag = (good >= 112) ? 1 : 0;
        if (blockIdx.x == 0) g_flag = sflag;
    }
    __syncthreads();
    const int f = sflag;
    #define RD(p, i) (f ? (float)((const __hip_bfloat16*)(p))[i] : ((const float*)(p))[i])
    const int tid = threadIdx.x;
    if (blockIdx.x == 0) {
        for (int idx = tid; idx < 120; idx += blockDim.x) {
            const int s = idx / 12, cc = idx - s*12;
            g_w[PWO1 + idx] = (cc < 11) ? RD(wo1v, s*11 + cc) : RD(bo1v, s);
        }
        for (int idx = tid; idx < 10; idx += blockDim.x) g_w[PWO2 + idx] = RD(wo2v, idx);
        if (tid == 0) { g_w[PBO2] = RD(bo2v, 0); g_w[PBO2+1] = 0.f; }
    }
    for (int idx = blockIdx.x*blockDim.x + tid; idx < NWF; idx += gridDim.x*blockDim.x) {
        float val = 0.f;
        if (idx < OFR) {
            // P1 B-frag: B[k][col=(e,s)]; k 16..25 -> Win[e][s][k-16], k 26 -> b_in
            const int nt = idx >> 9, rem = idx & 511, lane = rem >> 3, j = rem & 7;
            const int k = ((lane >> 4) << 3) + j, col = nt*16 + (lane & 15);
            if (col < 30) {
                const int e = col / 10, s = col - e*10;
                if (k >= 16 && k < 26) val = RD(winv, e*100 + s*10 + (k-16));
                else if (k == 26)      val = RD(binv, e*10 + s);
            }
        } else if (idx < OFH) {
            // P3 A-frags Wr/Wz: A[row=s][k]; k<10 -> W[s][k], 16..25 -> W[s][10+..], 26 -> bias
            const int i2 = idx - OFR;
            const int mt = i2 >> 9, rem = i2 & 511, lane = rem >> 3, j = rem & 7;
            const int k = ((lane >> 4) << 3) + j, s = lane & 15;
            if (s < 10) {
                const void* Wv = mt ? wzv : wrv;
                const void* bv = mt ? bzv : brv;
                if (k < 10)                 val = RD(Wv, s*20 + k);
                else if (k >= 16 && k < 26) val = RD(Wv, s*20 + 10 + (k-16));
                else if (k == 26)           val = RD(bv, s);
            }
        } else if (idx < OFA) {
            const int i2 = idx - OFH;
            const int lane = i2 >> 3, j = i2 & 7;
            const int k = ((lane >> 4) << 3) + j, s = lane & 15;
            if (s < 10) {
                if (k < 10)                 val = RD(whv, s*20 + k);
                else if (k >= 16 && k < 26) val = RD(whv, s*20 + 10 + (k-16));
                else if (k == 26)           val = RD(bhv, s);
            }
        } else {
            // adjacency frag: A[m=node][k=e*72+mm]; zero at pads
            const int i2 = idx - OFA;
            const int w = i2 / 3584, rem = i2 - w*3584;
            const int kt = rem >> 9, r2 = rem & 511, lane = r2 >> 3, j = r2 & 7;
            const int m = w*16 + (lane & 15);
            const int k = kt*32 + ((lane >> 4) << 3) + j;
            const int e = k / 72, mm = k - e*72;
            if (m < NN && e < 3 && mm < NN) val = RD(Av, m*210 + e*70 + mm);
        }
        g_wf[idx] = (_Float16)val;
    }
    #undef RD
}

template<typename T>
__device__ __forceinline__ void run2(const void* annv, void* outv,
                                     Smem& s0, Smem& s1, const int g0, const int g1)
{
    const T* ann_g = (const T*)annv;
    T* out_g       = (T*)outv;
    const int lane = threadIdx.x;    // single wave
    const int q    = lane >> 4;
    const int c    = lane & 15;
    const float* __restrict__ gw = g_w;

    // ---- shared fragment preload (ONE set serves BOTH graphs; loop-hoisted
    //      array form = r4's winning schedule; no sched_barrier pinning)
    const v8h w1f0 = *(const v8h*)&g_wf[       lane*8];
    const v8h w1f1 = *(const v8h*)&g_wf[512  + lane*8];
    const v8h wrf  = *(const v8h*)&g_wf[OFR  + lane*8];
    const v8h wzf  = *(const v8h*)&g_wf[OFZ  + lane*8];
    const v8h whf  = *(const v8h*)&g_wf[OFH  + lane*8];
    v8h adj[35];
    #pragma unroll
    for (int i = 0; i < 35; ++i)
        adj[i] = *(const v8h*)&g_wf[OFA + i*512 + lane*8];

    // ---- zero both LDS slices (phantom rows/cols MUST be finite-zero)
    {
        const int4 zz = {0,0,0,0};
        int4* z0 = (int4*)&s0;
        int4* z1 = (int4*)&s1;
        #pragma unroll 4
        for (int i = lane; i < (int)(sizeof(Smem)/16); i += TPB) { z0[i] = zz; z1[i] = zz; }
    }
    __syncthreads();

    // ---- seed both graphs: prop[0]=ann at k=16, bias-one at k=26
    for (int n2 = lane; n2 < NN; n2 += TPB) {
        s0.cat[n2*CATN + 16] = (_Float16)(float)ann_g[g0*NN + n2];
        s1.cat[n2*CATN + 16] = (_Float16)(float)ann_g[g1*NN + n2];
        s0.cat[n2*CATN + 26] = (_Float16)1.0f;
        s1.cat[n2*CATN + 26] = (_Float16)1.0f;
    }
    __syncthreads();

    // ---- P1 (paired): ins(prop) -> U for both graphs, interleaved per mt
    #define PHASE1() do {                                                        \
        _Pragma("unroll")                                                        \
        for (int mt = 0; mt < 5; ++mt) {                                         \
            const v8h af0 = *(const v8h*)&s0.cat[(mt*16 + c)*CATN + q*8];        \
            const v8h af1 = *(const v8h*)&s1.cat[(mt*16 + c)*CATN + q*8];        \
            const int node0 = mt*16 + q*4;                                       \
            _Pragma("unroll")                                                    \
            for (int nt = 0; nt < 2; ++nt) {                                     \
                const v8h wb = nt ? w1f1 : w1f0;                                 \
                v4f a0 = {0.f,0.f,0.f,0.f}, a1 = {0.f,0.f,0.f,0.f};              \
                a0 = __builtin_amdgcn_mfma_f32_16x16x32_f16(af0, wb, a0, 0,0,0); \
                a1 = __builtin_amdgcn_mfma_f32_16x16x32_f16(af1, wb, a1, 0,0,0); \
                const int colw = nt*16 + c;                                      \
                if (colw < 30 && node0 <= 68) {                                  \
                    const int e = colw / 10, s = colw - e*10;                    \
                    *(v4h*)&s0.U[s*USTR + e*72 + node0] =                        \
                        (v4h){(_Float16)a0[0],(_Float16)a0[1],                   \
                              (_Float16)a0[2],(_Float16)a0[3]};                  \
                    *(v4h*)&s1.U[s*USTR + e*72 + node0] =                        \
                        (v4h){(_Float16)a1[0],(_Float16)a1[1],                   \
                              (_Float16)a1[2],(_Float16)a1[3]};                  \
                }                                                                \
            }                                                                    \
        }                                                                        \
    } while(0)

    PHASE1();
    __syncthreads();

    #pragma unroll 1
    for (int step = 0; step < STEPS; ++step) {
        // ---- P2 (paired, operand-swapped): each adj frag feeds BOTH graphs'
        //      MFMAs back-to-back (one reload serves two uses -- r2 lesson).
        {
            v8h bfr0[7], bfr1[7];
            #pragma unroll
            for (int kt = 0; kt < 7; ++kt) {
                bfr0[kt] = *(const v8h*)&s0.U[c*USTR + q*8 + kt*32];
                bfr1[kt] = *(const v8h*)&s1.U[c*USTR + q*8 + kt*32];
            }
            #pragma unroll
            for (int mt = 0; mt < 5; ++mt) {
                v4f a0 = {0.f,0.f,0.f,0.f}, a1 = {0.f,0.f,0.f,0.f};
                #pragma unroll
                for (int kt = 0; kt < 7; ++kt) {
                    const v8h av = adj[mt*7+kt];
                    a0 = __builtin_amdgcn_mfma_f32_16x16x32_f16(bfr0[kt], av, a0, 0,0,0);
                    a1 = __builtin_amdgcn_mfma_f32_16x16x32_f16(bfr1[kt], av, a1, 0,0,0);
                }
                const int node = mt*16 + c;
                if (node < NN) {
                    const v4h h0 = {(_Float16)a0[0],(_Float16)a0[1],
                                    (_Float16)a0[2],(_Float16)a0[3]};
                    const v4h h1 = {(_Float16)a1[0],(_Float16)a1[1],
                                    (_Float16)a1[2],(_Float16)a1[3]};
                    _Float16* w0 = &s0.cat[node*CATN + q*4];   // s = q*4..q*4+3
                    _Float16* w1 = &s1.cat[node*CATN + q*4];
                    if (q < 2)       { *(v4h*)w0 = h0; *(v4h*)w1 = h1; }
                    else if (q == 2) { *(v2h*)w0 = (v2h){h0[0], h0[1]};
                                       *(v2h*)w1 = (v2h){h1[0], h1[1]}; }
                }
            }
        }
        __syncthreads();   // a_in visible

        // ---- P3 phase A (paired): r,z + rp-write, all 5 node-tiles, ONE fence
        v4h zgp0[5], pgp0[5], zgp1[5], pgp1[5];
        {
            #pragma unroll
            for (int nt = 0; nt < 5; ++nt) {
                const int node = nt*16 + c;
                const v8h bf0 = *(const v8h*)&s0.cat[node*CATN + q*8];
                const v8h bf1 = *(const v8h*)&s1.cat[node*CATN + q*8];
                v4f ar0 = {0.f,0.f,0.f,0.f}, az0 = {0.f,0.f,0.f,0.f};
                v4f ar1 = {0.f,0.f,0.f,0.f}, az1 = {0.f,0.f,0.f,0.f};
                ar0 = __builtin_amdgcn_mfma_f32_16x16x32_f16(wrf, bf0, ar0, 0,0,0);
                ar1 = __builtin_amdgcn_mfma_f32_16x16x32_f16(wrf, bf1, ar1, 0,0,0);
                az0 = __builtin_amdgcn_mfma_f32_16x16x32_f16(wzf, bf0, az0, 0,0,0);
                az1 = __builtin_amdgcn_mfma_f32_16x16x32_f16(wzf, bf1, az1, 0,0,0);
                const v4h pv0 = *(const v4h*)&s0.cat[node*CATN + 16 + q*4];
                const v4h pv1 = *(const v4h*)&s1.cat[node*CATN + 16 + q*4];
                v4h rp0, zh0, rp1, zh1;
                #pragma unroll
                for (int i = 0; i < 4; ++i) {
                    const float p0 = (float)pv0[i], p1 = (float)pv1[i];
                    zh0[i] = (_Float16)fast_sigmoid(az0[i]);
                    zh1[i] = (_Float16)fast_sigmoid(az1[i]);
                    rp0[i] = (_Float16)(fast_sigmoid(ar0[i]) * p0);
                    rp1[i] = (_Float16)(fast_sigmoid(ar1[i]) * p1);
                }
                zgp0[nt] = zh0; pgp0[nt] = pv0;
                zgp1[nt] = zh1; pgp1[nt] = pv1;
                if (node < NN) {
                    _Float16* w0 = &s0.cat[node*CATN + 16 + q*4];
                    _Float16* w1 = &s1.cat[node*CATN + 16 + q*4];
                    if (q < 2)       { *(v4h*)w0 = rp0; *(v4h*)w1 = rp1; }
                    else if (q == 2) { *(v2h*)w0 = (v2h){rp0[0], rp0[1]};
                                       *(v2h*)w1 = (v2h){rp1[0], rp1[1]}; }
                }
            }
        }
        __syncthreads();   // rp visible cross-lane

        // ---- P3 phase B (paired): h + state update, all 5 node-tiles
        {
            #pragma unroll
            for (int nt = 0; nt < 5; ++nt) {
                const int node = nt*16 + c;
                const v8h bf0 = *(const v8h*)&s0.cat[node*CATN + q*8];
                const v8h bf1 = *(const v8h*)&s1.cat[node*CATN + q*8];
                v4f ah0 = {0.f,0.f,0.f,0.f}, ah1 = {0.f,0.f,0.f,0.f};
                ah0 = __builtin_amdgcn_mfma_f32_16x16x32_f16(whf, bf0, ah0, 0,0,0);
                ah1 = __builtin_amdgcn_mfma_f32_16x16x32_f16(whf, bf1, ah1, 0,0,0);
                v4h pn0, pn1;
                #pragma unroll
                for (int i = 0; i < 4; ++i) {
                    const float h0 = fast_tanh(ah0[i]);
                    const float h1 = fast_tanh(ah1[i]);
                    const float p0 = (float)pgp0[nt][i], z0 = (float)zgp0[nt][i];
                    const float p1 = (float)pgp1[nt][i], z1 = (float)zgp1[nt][i];
                    pn0[i] = (_Float16)(p0 + z0*(h0 - p0));
                    pn1[i] = (_Float16)(p1 + z1*(h1 - p1));
                }
                if (node < NN) {
                    _Float16* w0 = &s0.cat[node*CATN + 16 + q*4];
                    _Float16* w1 = &s1.cat[node*CATN + 16 + q*4];
                    if (q < 2)       { *(v4h*)w0 = pn0; *(v4h*)w1 = pn1; }
                    else if (q == 2) { *(v2h*)w0 = (v2h){pn0[0], pn0[1]};
                                       *(v2h*)w1 = (v2h){pn1[0], pn1[1]}; }
                }
            }
        }
        __syncthreads();   // new prop visible

        // ---- P1 for next step
        if (step < STEPS-1) {
            PHASE1();
            __syncthreads();
        }
    }
    #undef PHASE1

    // ---- epilogue: one output per node, both graphs
    for (int n2 = lane; n2 < NN; n2 += TPB) {
        const float av0 = (float)ann_g[g0*NN + n2];
        const float av1 = (float)ann_g[g1*NN + n2];
        float pr0[10], pr1[10];
        {
            const v8h p8 = *(const v8h*)&s0.cat[n2*CATN + 16];
            const v2h p2 = *(const v2h*)&s0.cat[n2*CATN + 24];
            #pragma unroll
            for (int i = 0; i < 8; ++i) pr0[i] = (float)p8[i];
            pr0[8] = (float)p2[0]; pr0[9] = (float)p2[1];
        }
        {
            const v8h p8 = *(const v8h*)&s1.cat[n2*CATN + 16];
            const v2h p2 = *(const v2h*)&s1.cat[n2*CATN + 24];
            #pragma unroll
            for (int i = 0; i < 8; ++i) pr1[i] = (float)p8[i];
            pr1[8] = (float)p2[0]; pr1[9] = (float)p2[1];
        }
        float o0 = gw[PBO2], o1 = gw[PBO2];
        #pragma unroll
        for (int s = 0; s < 10; ++s) {
            const float* wr_ = &gw[PWO1 + s*12];
            float a0 = wr_[11] + wr_[10]*av0;
            float a1 = wr_[11] + wr_[10]*av1;
            #pragma unroll
            for (int d = 0; d < 10; ++d) { a0 += pr0[d]*wr_[d]; a1 += pr1[d]*wr_[d]; }
            o0 += fast_tanh(a0) * gw[PWO2 + s];
            o1 += fast_tanh(a1) * gw[PWO2 + s];
        }
        out_g[g0*NN + n2] = (T)o0;
        out_g[g1*NN + n2] = (T)o1;
    }
}

// amdgpu_waves_per_eu(2,2): pin occupancy to EXACTLY 2 waves/EU so the
// allocator gets the full 256-VGPR budget and stops volunteering for the
// 128-tier (r8: squeezed to 128 and spilled 37 MB; r1: same at 64-tier).
// LDS 22528 -> 7 blocks/CU is the real residency bound (= observed slots).
// Tripwires: VGPR ~128 => attribute ignored; WRITE_SIZE >> 4.9 MB at VGPR
// ~256 => live set > 256 => drop paired zgp/pgp batching.
__global__ __attribute__((amdgpu_flat_work_group_size(TPB, TPB)))
           __attribute__((amdgpu_waves_per_eu(2, 2)))
void ggnn_kernel(const void* annv, void* outv)
{
    __shared__ Smem sm0, sm1;
    const int g0 = blockIdx.x * GPW;
    if (g_flag)
        run2<__hip_bfloat16>(annv, outv, sm0, sm1, g0, g0+1);
    else
        run2<float>(annv, outv, sm0, sm1, g0, g0+1);
}

extern "C" void kernel_launch(void* const* d_in, const int* in_sizes, int n_in,
                              void* d_out, int out_size, void* d_ws, size_t ws_size,
                              hipStream_t stream) {
    (void)in_sizes; (void)n_in; (void)out_size; (void)d_ws; (void)ws_size;
    hipLaunchKernelGGL(prep_kernel, dim3(PREPB), dim3(256), 0, stream,
        d_in[0], d_in[1], d_in[2], d_in[3], d_in[4], d_in[5], d_in[6],
        d_in[7], d_in[8], d_in[9], d_in[10], d_in[11], d_in[12], d_in[13]);
    hipLaunchKernelGGL(ggnn_kernel, dim3(NBLK), dim3(TPB), 0, stream,
        d_in[0], d_out);
}

// Round 11
// 279.190 us; speedup vs baseline: 1.0242x; 1.0242x over previous
//
#include <hip/hip_runtime.h>
#include <hip/hip_bf16.h>

typedef _Float16 v8h __attribute__((ext_vector_type(8)));
typedef _Float16 v4h __attribute__((ext_vector_type(4)));
typedef _Float16 v2h __attribute__((ext_vector_type(2)));
typedef float    v4f __attribute__((ext_vector_type(4)));

#define NTOT  16384
#define NN    70
#define STEPS 5
#define TPB   64                     // ONE wave per block
#define GPW   2                      // TWO independent graphs per wave (ILP)
#define NBLK  (NTOT/GPW)             // 8192 blocks
// r10 lesson: two-graph ILP already wins per-graph (19.4 vs 22.2 us/graph)
// DESPITE a 38MB spill tax. The 256-VGPR budget is unobtainable (r8/r10:
// allocator pins 128 under both launch_bounds and waves_per_eu). So shrink
// the live set to FIT 128: drop the adj[35] hoist (140 VGPR fiction; r4's
// compiler rematerialized from L2 anyway) -> use-site adj loads, each feeding
// BOTH graphs' MFMAs. Live set ~115: bfr 56 + adj window + accs + misc.
#define CATN  40                     // cat node stride (r6-validated)
#define CATH  3208                   // 80 nodes * 40 + pad
#define USTR  232                    // U col stride (halves): 116 dw == 20 mod 32
#define UH    (10*USTR)              // 10 real cols; phantom-col B-frag reads
                                     // (c>=10) land in same graph's cat: finite,
                                     // D rows 10..15 discarded (r2/r3/r6-validated)

// epilogue weights (fp32, global scalar loads)
#define PWO1 0                       // 10 rows x 12: [Wo1[s][0..9], ann_coef, bo1[s]]
#define PWO2 120
#define PBO2 130
#define NWP  132

// fp16 fragment images (built by prep):
//  [0..1023]     P1 B-frags Wstack, 2 tiles:  nt*512 + lane*8 + j
//  [1024..2047]  P3 A-frags Wr | Wz:          mt*512 + lane*8 + j
//  [2048..2559]  P3 A-frag  Wh:               lane*8 + j
//  [2560..20479] adjacency frags:             2560 + (mt*7+kt)*512 + lane*8 + j
//  NOTE: A-frag image of M == B-frag image of M^T for 16x16x32 (identical
//  (lane,j)->(row/col,k) map), so adjacency images serve as swapped-P2's B operand.
#define OFR  1024
#define OFZ  1536
#define OFH  2048
#define OFA  2560
#define NWF  20480
#define PREPB 40

__device__ __align__(16) float    g_w[NWP];
__device__ __align__(16) _Float16 g_wf[NWF];
__device__ int g_flag;

__device__ __forceinline__ float fast_sigmoid(float x) {
    return __builtin_amdgcn_rcpf(1.0f + __expf(-x));
}
__device__ __forceinline__ float fast_tanh(float x) {
    float ax = fabsf(x);
    float e  = __expf(-2.0f * ax);
    float t  = (1.0f - e) * __builtin_amdgcn_rcpf(1.0f + e);
    return copysignf(t, x);
}

struct __align__(16) Smem {
    _Float16 U[UH];      // 4640 B: U[col=s][k=e*72+node]
    _Float16 cat[CATH];  // 6416 B: cat[node][k]; k0..9=a_in, 16..25=prop, 26=1
};
// 11056 B per graph; block = 2 graphs = 22112 B -> alloc 22528 -> 7 blocks/CU
// holding 14 graphs in flight (vs r6's 7).

// ---- prep: probe dtype; build epilogue weights + all fp16 fragment images ----
__global__ void prep_kernel(const void* annv, const void* Av,
    const void* winv, const void* binv, const void* wrv, const void* brv,
    const void* wzv, const void* bzv, const void* whv, const void* bhv,
    const void* wo1v, const void* bo1v, const void* wo2v, const void* bo2v)
{
    __shared__ int sflag;
    if (threadIdx.x == 0) {
        const unsigned short* u = (const unsigned short*)annv;
        int good = 0;
        for (int k = 0; k < 128; ++k) {
            unsigned short bb = u[k];
            int ex = (bb >> 7) & 0xFF;
            if (bb == 0 || (ex >= 101 && ex <= 131)) ++good;
        }
        sflag = (good >= 112) ? 1 : 0;
        if (blockIdx.x == 0) g_flag = sflag;
    }
    __syncthreads();
    const int f = sflag;
    #define RD(p, i) (f ? (float)((const __hip_bfloat16*)(p))[i] : ((const float*)(p))[i])
    const int tid = threadIdx.x;
    if (blockIdx.x == 0) {
        for (int idx = tid; idx < 120; idx += blockDim.x) {
            const int s = idx / 12, cc = idx - s*12;
            g_w[PWO1 + idx] = (cc < 11) ? RD(wo1v, s*11 + cc) : RD(bo1v, s);
        }
        for (int idx = tid; idx < 10; idx += blockDim.x) g_w[PWO2 + idx] = RD(wo2v, idx);
        if (tid == 0) { g_w[PBO2] = RD(bo2v, 0); g_w[PBO2+1] = 0.f; }
    }
    for (int idx = blockIdx.x*blockDim.x + tid; idx < NWF; idx += gridDim.x*blockDim.x) {
        float val = 0.f;
        if (idx < OFR) {
            // P1 B-frag: B[k][col=(e,s)]; k 16..25 -> Win[e][s][k-16], k 26 -> b_in
            const int nt = idx >> 9, rem = idx & 511, lane = rem >> 3, j = rem & 7;
            const int k = ((lane >> 4) << 3) + j, col = nt*16 + (lane & 15);
            if (col < 30) {
                const int e = col / 10, s = col - e*10;
                if (k >= 16 && k < 26) val = RD(winv, e*100 + s*10 + (k-16));
                else if (k == 26)      val = RD(binv, e*10 + s);
            }
        } else if (idx < OFH) {
            // P3 A-frags Wr/Wz: A[row=s][k]; k<10 -> W[s][k], 16..25 -> W[s][10+..], 26 -> bias
            const int i2 = idx - OFR;
            const int mt = i2 >> 9, rem = i2 & 511, lane = rem >> 3, j = rem & 7;
            const int k = ((lane >> 4) << 3) + j, s = lane & 15;
            if (s < 10) {
                const void* Wv = mt ? wzv : wrv;
                const void* bv = mt ? bzv : brv;
                if (k < 10)                 val = RD(Wv, s*20 + k);
                else if (k >= 16 && k < 26) val = RD(Wv, s*20 + 10 + (k-16));
                else if (k == 26)           val = RD(bv, s);
            }
        } else if (idx < OFA) {
            const int i2 = idx - OFH;
            const int lane = i2 >> 3, j = i2 & 7;
            const int k = ((lane >> 4) << 3) + j, s = lane & 15;
            if (s < 10) {
                if (k < 10)                 val = RD(whv, s*20 + k);
                else if (k >= 16 && k < 26) val = RD(whv, s*20 + 10 + (k-16));
                else if (k == 26)           val = RD(bhv, s);
            }
        } else {
            // adjacency frag: A[m=node][k=e*72+mm]; zero at pads
            const int i2 = idx - OFA;
            const int w = i2 / 3584, rem = i2 - w*3584;
            const int kt = rem >> 9, r2 = rem & 511, lane = r2 >> 3, j = r2 & 7;
            const int m = w*16 + (lane & 15);
            const int k = kt*32 + ((lane >> 4) << 3) + j;
            const int e = k / 72, mm = k - e*72;
            if (m < NN && e < 3 && mm < NN) val = RD(Av, m*210 + e*70 + mm);
        }
        g_wf[idx] = (_Float16)val;
    }
    #undef RD
}

template<typename T>
__device__ __forceinline__ void run2(const void* annv, void* outv,
                                     Smem& s0, Smem& s1, const int g0, const int g1)
{
    const T* ann_g = (const T*)annv;
    T* out_g       = (T*)outv;
    const int lane = threadIdx.x;    // single wave
    const int q    = lane >> 4;
    const int c    = lane & 15;
    const float* __restrict__ gw = g_w;

    // ---- weight fragments only (NO adj hoist: 140-VGPR demand caused the
    //      r8/r10 spill; adjacency is loaded at use site in P2, one load
    //      feeding both graphs' MFMAs, scheduler free to batch ahead)
    const v8h w1f0 = *(const v8h*)&g_wf[       lane*8];
    const v8h w1f1 = *(const v8h*)&g_wf[512  + lane*8];
    const v8h wrf  = *(const v8h*)&g_wf[OFR  + lane*8];
    const v8h wzf  = *(const v8h*)&g_wf[OFZ  + lane*8];
    const v8h whf  = *(const v8h*)&g_wf[OFH  + lane*8];

    // ---- zero both LDS slices (phantom rows/cols MUST be finite-zero)
    {
        const int4 zz = {0,0,0,0};
        int4* z0 = (int4*)&s0;
        int4* z1 = (int4*)&s1;
        #pragma unroll 4
        for (int i = lane; i < (int)(sizeof(Smem)/16); i += TPB) { z0[i] = zz; z1[i] = zz; }
    }
    __syncthreads();

    // ---- seed both graphs: prop[0]=ann at k=16, bias-one at k=26
    for (int n2 = lane; n2 < NN; n2 += TPB) {
        s0.cat[n2*CATN + 16] = (_Float16)(float)ann_g[g0*NN + n2];
        s1.cat[n2*CATN + 16] = (_Float16)(float)ann_g[g1*NN + n2];
        s0.cat[n2*CATN + 26] = (_Float16)1.0f;
        s1.cat[n2*CATN + 26] = (_Float16)1.0f;
    }
    __syncthreads();

    // ---- P1 (paired): ins(prop) -> U for both graphs, interleaved per mt
    #define PHASE1() do {                                                        \
        _Pragma("unroll")                                                        \
        for (int mt = 0; mt < 5; ++mt) {                                         \
            const v8h af0 = *(const v8h*)&s0.cat[(mt*16 + c)*CATN + q*8];        \
            const v8h af1 = *(const v8h*)&s1.cat[(mt*16 + c)*CATN + q*8];        \
            const int node0 = mt*16 + q*4;                                       \
            _Pragma("unroll")                                                    \
            for (int nt = 0; nt < 2; ++nt) {                                     \
                const v8h wb = nt ? w1f1 : w1f0;                                 \
                v4f a0 = {0.f,0.f,0.f,0.f}, a1 = {0.f,0.f,0.f,0.f};              \
                a0 = __builtin_amdgcn_mfma_f32_16x16x32_f16(af0, wb, a0, 0,0,0); \
                a1 = __builtin_amdgcn_mfma_f32_16x16x32_f16(af1, wb, a1, 0,0,0); \
                const int colw = nt*16 + c;                                      \
                if (colw < 30 && node0 <= 68) {                                  \
                    const int e = colw / 10, s = colw - e*10;                    \
                    *(v4h*)&s0.U[s*USTR + e*72 + node0] =                        \
                        (v4h){(_Float16)a0[0],(_Float16)a0[1],                   \
                              (_Float16)a0[2],(_Float16)a0[3]};                  \
                    *(v4h*)&s1.U[s*USTR + e*72 + node0] =                        \
                        (v4h){(_Float16)a1[0],(_Float16)a1[1],                   \
                              (_Float16)a1[2],(_Float16)a1[3]};                  \
                }                                                                \
            }                                                                    \
        }                                                                        \
    } while(0)

    PHASE1();
    __syncthreads();

    #pragma unroll 1
    for (int step = 0; step < STEPS; ++step) {
        // ---- P2 (paired, operand-swapped, use-site adj): each adj frag is
        //      loaded ONCE and feeds BOTH graphs' MFMAs. Unlike r2 (1 consumer,
        //      nothing to overlap), the dual consumers + alternating acc chains
        //      give the scheduler independent work per ~200cy L2 load.
        {
            v8h bfr0[7], bfr1[7];
            #pragma unroll
            for (int kt = 0; kt < 7; ++kt) {
                bfr0[kt] = *(const v8h*)&s0.U[c*USTR + q*8 + kt*32];
                bfr1[kt] = *(const v8h*)&s1.U[c*USTR + q*8 + kt*32];
            }
            #pragma unroll
            for (int mt = 0; mt < 5; ++mt) {
                v4f a0 = {0.f,0.f,0.f,0.f}, a1 = {0.f,0.f,0.f,0.f};
                #pragma unroll
                for (int kt = 0; kt < 7; ++kt) {
                    const v8h av = *(const v8h*)&g_wf[OFA + (mt*7+kt)*512 + lane*8];
                    a0 = __builtin_amdgcn_mfma_f32_16x16x32_f16(bfr0[kt], av, a0, 0,0,0);
                    a1 = __builtin_amdgcn_mfma_f32_16x16x32_f16(bfr1[kt], av, a1, 0,0,0);
                }
                const int node = mt*16 + c;
                if (node < NN) {
                    const v4h h0 = {(_Float16)a0[0],(_Float16)a0[1],
                                    (_Float16)a0[2],(_Float16)a0[3]};
                    const v4h h1 = {(_Float16)a1[0],(_Float16)a1[1],
                                    (_Float16)a1[2],(_Float16)a1[3]};
                    _Float16* w0 = &s0.cat[node*CATN + q*4];   // s = q*4..q*4+3
                    _Float16* w1 = &s1.cat[node*CATN + q*4];
                    if (q < 2)       { *(v4h*)w0 = h0; *(v4h*)w1 = h1; }
                    else if (q == 2) { *(v2h*)w0 = (v2h){h0[0], h0[1]};
                                       *(v2h*)w1 = (v2h){h1[0], h1[1]}; }
                }
            }
        }
        __syncthreads();   // a_in visible

        // ---- P3 phase A (paired): r,z + rp-write, all 5 node-tiles, ONE fence
        v4h zgp0[5], pgp0[5], zgp1[5], pgp1[5];
        {
            #pragma unroll
            for (int nt = 0; nt < 5; ++nt) {
                const int node = nt*16 + c;
                const v8h bf0 = *(const v8h*)&s0.cat[node*CATN + q*8];
                const v8h bf1 = *(const v8h*)&s1.cat[node*CATN + q*8];
                v4f ar0 = {0.f,0.f,0.f,0.f}, az0 = {0.f,0.f,0.f,0.f};
                v4f ar1 = {0.f,0.f,0.f,0.f}, az1 = {0.f,0.f,0.f,0.f};
                ar0 = __builtin_amdgcn_mfma_f32_16x16x32_f16(wrf, bf0, ar0, 0,0,0);
                ar1 = __builtin_amdgcn_mfma_f32_16x16x32_f16(wrf, bf1, ar1, 0,0,0);
                az0 = __builtin_amdgcn_mfma_f32_16x16x32_f16(wzf, bf0, az0, 0,0,0);
                az1 = __builtin_amdgcn_mfma_f32_16x16x32_f16(wzf, bf1, az1, 0,0,0);
                const v4h pv0 = *(const v4h*)&s0.cat[node*CATN + 16 + q*4];
                const v4h pv1 = *(const v4h*)&s1.cat[node*CATN + 16 + q*4];
                v4h rp0, zh0, rp1, zh1;
                #pragma unroll
                for (int i = 0; i < 4; ++i) {
                    const float p0 = (float)pv0[i], p1 = (float)pv1[i];
                    zh0[i] = (_Float16)fast_sigmoid(az0[i]);
                    zh1[i] = (_Float16)fast_sigmoid(az1[i]);
                    rp0[i] = (_Float16)(fast_sigmoid(ar0[i]) * p0);
                    rp1[i] = (_Float16)(fast_sigmoid(ar1[i]) * p1);
                }
                zgp0[nt] = zh0; pgp0[nt] = pv0;
                zgp1[nt] = zh1; pgp1[nt] = pv1;
                if (node < NN) {
                    _Float16* w0 = &s0.cat[node*CATN + 16 + q*4];
                    _Float16* w1 = &s1.cat[node*CATN + 16 + q*4];
                    if (q < 2)       { *(v4h*)w0 = rp0; *(v4h*)w1 = rp1; }
                    else if (q == 2) { *(v2h*)w0 = (v2h){rp0[0], rp0[1]};
                                       *(v2h*)w1 = (v2h){rp1[0], rp1[1]}; }
                }
            }
        }
        __syncthreads();   // rp visible cross-lane

        // ---- P3 phase B (paired): h + state update, all 5 node-tiles
        {
            #pragma unroll
            for (int nt = 0; nt < 5; ++nt) {
                const int node = nt*16 + c;
                const v8h bf0 = *(const v8h*)&s0.cat[node*CATN + q*8];
                const v8h bf1 = *(const v8h*)&s1.cat[node*CATN + q*8];
                v4f ah0 = {0.f,0.f,0.f,0.f}, ah1 = {0.f,0.f,0.f,0.f};
                ah0 = __builtin_amdgcn_mfma_f32_16x16x32_f16(whf, bf0, ah0, 0,0,0);
                ah1 = __builtin_amdgcn_mfma_f32_16x16x32_f16(whf, bf1, ah1, 0,0,0);
                v4h pn0, pn1;
                #pragma unroll
                for (int i = 0; i < 4; ++i) {
                    const float h0 = fast_tanh(ah0[i]);
                    const float h1 = fast_tanh(ah1[i]);
                    const float p0 = (float)pgp0[nt][i], z0 = (float)zgp0[nt][i];
                    const float p1 = (float)pgp1[nt][i], z1 = (float)zgp1[nt][i];
                    pn0[i] = (_Float16)(p0 + z0*(h0 - p0));
                    pn1[i] = (_Float16)(p1 + z1*(h1 - p1));
                }
                if (node < NN) {
                    _Float16* w0 = &s0.cat[node*CATN + 16 + q*4];
                    _Float16* w1 = &s1.cat[node*CATN + 16 + q*4];
                    if (q < 2)       { *(v4h*)w0 = pn0; *(v4h*)w1 = pn1; }
                    else if (q == 2) { *(v2h*)w0 = (v2h){pn0[0], pn0[1]};
                                       *(v2h*)w1 = (v2h){pn1[0], pn1[1]}; }
                }
            }
        }
        __syncthreads();   // new prop visible

        // ---- P1 for next step
        if (step < STEPS-1) {
            PHASE1();
            __syncthreads();
        }
    }
    #undef PHASE1

    // ---- epilogue: one output per node, both graphs
    for (int n2 = lane; n2 < NN; n2 += TPB) {
        const float av0 = (float)ann_g[g0*NN + n2];
        const float av1 = (float)ann_g[g1*NN + n2];
        float pr0[10], pr1[10];
        {
            const v8h p8 = *(const v8h*)&s0.cat[n2*CATN + 16];
            const v2h p2 = *(const v2h*)&s0.cat[n2*CATN + 24];
            #pragma unroll
            for (int i = 0; i < 8; ++i) pr0[i] = (float)p8[i];
            pr0[8] = (float)p2[0]; pr0[9] = (float)p2[1];
        }
        {
            const v8h p8 = *(const v8h*)&s1.cat[n2*CATN + 16];
            const v2h p2 = *(const v2h*)&s1.cat[n2*CATN + 24];
            #pragma unroll
            for (int i = 0; i < 8; ++i) pr1[i] = (float)p8[i];
            pr1[8] = (float)p2[0]; pr1[9] = (float)p2[1];
        }
        float o0 = gw[PBO2], o1 = gw[PBO2];
        #pragma unroll
        for (int s = 0; s < 10; ++s) {
            const float* wr_ = &gw[PWO1 + s*12];
            float a0 = wr_[11] + wr_[10]*av0;
            float a1 = wr_[11] + wr_[10]*av1;
            #pragma unroll
            for (int d = 0; d < 10; ++d) { a0 += pr0[d]*wr_[d]; a1 += pr1[d]*wr_[d]; }
            o0 += fast_tanh(a0) * gw[PWO2 + s];
            o1 += fast_tanh(a1) * gw[PWO2 + s];
        }
        out_g[g0*NN + n2] = (T)o0;
        out_g[g1*NN + n2] = (T)o1;
    }
}

// __launch_bounds__(64,2): the bound under which r4/r6 landed 120 VGPR no-spill.
// Live set now ~115 (bfr 56 + adj window + accs + weights rematerializable),
// so the 128 tier should hold WITHOUT spilling (r8/r10 spilled because the
// adj[35] hoist demanded ~230). Tripwires: WRITE_SIZE >> 4.9MB => still
// spilling => the 2-graph path is infeasible, revert to r6; dur >= 210 with
// clean WRITE_SIZE => use-site adj latency dominates => revert to r6.
__global__ __launch_bounds__(TPB, 2)
void ggnn_kernel(const void* annv, void* outv)
{
    __shared__ Smem sm0, sm1;
    const int g0 = blockIdx.x * GPW;
    if (g_flag)
        run2<__hip_bfloat16>(annv, outv, sm0, sm1, g0, g0+1);
    else
        run2<float>(annv, outv, sm0, sm1, g0, g0+1);
}

extern "C" void kernel_launch(void* const* d_in, const int* in_sizes, int n_in,
                              void* d_out, int out_size, void* d_ws, size_t ws_size,
                              hipStream_t stream) {
    (void)in_sizes; (void)n_in; (void)out_size; (void)d_ws; (void)ws_size;
    hipLaunchKernelGGL(prep_kernel, dim3(PREPB), dim3(256), 0, stream,
        d_in[0], d_in[1], d_in[2], d_in[3], d_in[4], d_in[5], d_in[6],
        d_in[7], d_in[8], d_in[9], d_in[10], d_in[11], d_in[12], d_in[13]);
    hipLaunchKernelGGL(ggnn_kernel, dim3(NBLK), dim3(TPB), 0, stream,
        d_in[0], d_out);
}

// Round 12
// 259.220 us; speedup vs baseline: 1.1031x; 1.0770x over previous
//
#include <hip/hip_runtime.h>
#include <hip/hip_bf16.h>

typedef _Float16 v8h __attribute__((ext_vector_type(8)));
typedef _Float16 v4h __attribute__((ext_vector_type(4)));
typedef _Float16 v2h __attribute__((ext_vector_type(2)));
typedef float    v4f __attribute__((ext_vector_type(4)));
typedef int      v4i __attribute__((ext_vector_type(4)));
typedef int      v2i __attribute__((ext_vector_type(2)));

#define NTOT  16384
#define NN    70
#define STEPS 5
#define TPB   64                     // ONE wave per block; one graph per block
#define NBLK  NTOT                   // r6 structure: the verified best (201.5us)
// r7-r11 verdict: every multi-graph/occupancy structure loses to r6 —
// ~7 wave-slots/CU is the ceiling in ALL configs (even 4-wave WGs, r7).
// This round attacks per-wave critical-path latency on the r6 base:
//  (a) P3 fused: rp exchanged via ds_bpermute in-register (rows are
//      tile-disjoint) -> no rp LDS write, no bf2 reload, one less
//      barrier+lgkm drain per step (4->3 barriers).
//  (b) f32->f16 via v_cvt_pkrtz pairs (RTZ) on U/a_in/rp; pn stays RNE.
#define CATN  40                     // cat node stride (r6-validated)
#define CATH  3208                   // 80 nodes * 40 + pad
#define USTR  232                    // U col stride (halves): 116 dw == 20 mod 32
#define UH    (10*USTR)              // 10 real cols; phantom-col B-frag reads
                                     // (c>=10) land in cat: finite, D rows
                                     // 10..15 discarded (r2/r3/r6-validated)

// epilogue weights (fp32, global scalar loads)
#define PWO1 0                       // 10 rows x 12: [Wo1[s][0..9], ann_coef, bo1[s]]
#define PWO2 120
#define PBO2 130
#define NWP  132

// fp16 fragment images (built by prep):
//  [0..1023]     P1 B-frags Wstack, 2 tiles:  nt*512 + lane*8 + j
//  [1024..2047]  P3 A-frags Wr | Wz:          mt*512 + lane*8 + j
//  [2048..2559]  P3 A-frag  Wh:               lane*8 + j
//  [2560..20479] adjacency frags:             2560 + (mt*7+kt)*512 + lane*8 + j
//  NOTE: A-frag image of M == B-frag image of M^T for 16x16x32 (identical
//  (lane,j)->(row/col,k) map), so adjacency images serve as swapped-P2's B operand.
#define OFR  1024
#define OFZ  1536
#define OFH  2048
#define OFA  2560
#define NWF  20480
#define PREPB 40

__device__ __align__(16) float    g_w[NWP];
__device__ __align__(16) _Float16 g_wf[NWF];
__device__ int g_flag;

__device__ __forceinline__ float fast_sigmoid(float x) {
    return __builtin_amdgcn_rcpf(1.0f + __expf(-x));
}
__device__ __forceinline__ float fast_tanh(float x) {
    float ax = fabsf(x);
    float e  = __expf(-2.0f * ax);
    float t  = (1.0f - e) * __builtin_amdgcn_rcpf(1.0f + e);
    return copysignf(t, x);
}
// packed f32x2 -> f16x2 (v_cvt_pkrtz): halves cvt issue count; RTZ rounding
// on intermediates only (U, a_in, rp) — state update pn stays RNE.
__device__ __forceinline__ v4h pk4(v4f a) {
    auto lo = __builtin_amdgcn_cvt_pkrtz(a[0], a[1]);
    auto hi = __builtin_amdgcn_cvt_pkrtz(a[2], a[3]);
    v4h r; r[0] = lo[0]; r[1] = lo[1]; r[2] = hi[0]; r[3] = hi[1];
    return r;
}

struct __align__(16) Smem {
    _Float16 U[UH];      // 4640 B: U[col=s][k=e*72+node]
    _Float16 cat[CATH];  // 6416 B: cat[node][k]; k0..9=a_in, 16..25=prop, 26=1
};
// 11056 B -> 11264 alloc (r6 geometry; occupancy invariant at ~7 waves/CU)

// ---- prep: probe dtype; build epilogue weights + all fp16 fragment images ----
__global__ void prep_kernel(const void* annv, const void* Av,
    const void* winv, const void* binv, const void* wrv, const void* brv,
    const void* wzv, const void* bzv, const void* whv, const void* bhv,
    const void* wo1v, const void* bo1v, const void* wo2v, const void* bo2v)
{
    __shared__ int sflag;
    if (threadIdx.x == 0) {
        const unsigned short* u = (const unsigned short*)annv;
        int good = 0;
        for (int k = 0; k < 128; ++k) {
            unsigned short bb = u[k];
            int ex = (bb >> 7) & 0xFF;
            if (bb == 0 || (ex >= 101 && ex <= 131)) ++good;
        }
        sflag = (good >= 112) ? 1 : 0;
        if (blockIdx.x == 0) g_flag = sflag;
    }
    __syncthreads();
    const int f = sflag;
    #define RD(p, i) (f ? (float)((const __hip_bfloat16*)(p))[i] : ((const float*)(p))[i])
    const int tid = threadIdx.x;
    if (blockIdx.x == 0) {
        for (int idx = tid; idx < 120; idx += blockDim.x) {
            const int s = idx / 12, cc = idx - s*12;
            g_w[PWO1 + idx] = (cc < 11) ? RD(wo1v, s*11 + cc) : RD(bo1v, s);
        }
        for (int idx = tid; idx < 10; idx += blockDim.x) g_w[PWO2 + idx] = RD(wo2v, idx);
        if (tid == 0) { g_w[PBO2] = RD(bo2v, 0); g_w[PBO2+1] = 0.f; }
    }
    for (int idx = blockIdx.x*blockDim.x + tid; idx < NWF; idx += gridDim.x*blockDim.x) {
        float val = 0.f;
        if (idx < OFR) {
            // P1 B-frag: B[k][col=(e,s)]; k 16..25 -> Win[e][s][k-16], k 26 -> b_in
            const int nt = idx >> 9, rem = idx & 511, lane = rem >> 3, j = rem & 7;
            const int k = ((lane >> 4) << 3) + j, col = nt*16 + (lane & 15);
            if (col < 30) {
                const int e = col / 10, s = col - e*10;
                if (k >= 16 && k < 26) val = RD(winv, e*100 + s*10 + (k-16));
                else if (k == 26)      val = RD(binv, e*10 + s);
            }
        } else if (idx < OFH) {
            // P3 A-frags Wr/Wz: A[row=s][k]; k<10 -> W[s][k], 16..25 -> W[s][10+..], 26 -> bias
            const int i2 = idx - OFR;
            const int mt = i2 >> 9, rem = i2 & 511, lane = rem >> 3, j = rem & 7;
            const int k = ((lane >> 4) << 3) + j, s = lane & 15;
            if (s < 10) {
                const void* Wv = mt ? wzv : wrv;
                const void* bv = mt ? bzv : brv;
                if (k < 10)                 val = RD(Wv, s*20 + k);
                else if (k >= 16 && k < 26) val = RD(Wv, s*20 + 10 + (k-16));
                else if (k == 26)           val = RD(bv, s);
            }
        } else if (idx < OFA) {
            const int i2 = idx - OFH;
            const int lane = i2 >> 3, j = i2 & 7;
            const int k = ((lane >> 4) << 3) + j, s = lane & 15;
            if (s < 10) {
                if (k < 10)                 val = RD(whv, s*20 + k);
                else if (k >= 16 && k < 26) val = RD(whv, s*20 + 10 + (k-16));
                else if (k == 26)           val = RD(bhv, s);
            }
        } else {
            // adjacency frag: A[m=node][k=e*72+mm]; zero at pads
            const int i2 = idx - OFA;
            const int w = i2 / 3584, rem = i2 - w*3584;
            const int kt = rem >> 9, r2 = rem & 511, lane = r2 >> 3, j = r2 & 7;
            const int m = w*16 + (lane & 15);
            const int k = kt*32 + ((lane >> 4) << 3) + j;
            const int e = k / 72, mm = k - e*72;
            if (m < NN && e < 3 && mm < NN) val = RD(Av, m*210 + e*70 + mm);
        }
        g_wf[idx] = (_Float16)val;
    }
    #undef RD
}

template<typename T>
__device__ __forceinline__ void run_impl(const void* annv, void* outv, Smem& sm)
{
    const T* ann_g = (const T*)annv;
    T* out_g       = (T*)outv;
    const int lane = threadIdx.x;    // single wave
    const int blk  = blockIdx.x;     // == graph id
    const int q    = lane >> 4;
    const int c    = lane & 15;
    const float* __restrict__ gw = g_w;

    // ---- preload fragments as loop-hoisted arrays (r4/r6 winning schedule;
    //      compiler keeps what fits in ~120 VGPR, batches reloads early)
    const v8h w1f0 = *(const v8h*)&g_wf[       lane*8];
    const v8h w1f1 = *(const v8h*)&g_wf[512  + lane*8];
    const v8h wrf  = *(const v8h*)&g_wf[OFR  + lane*8];
    const v8h wzf  = *(const v8h*)&g_wf[OFZ  + lane*8];
    const v8h whf  = *(const v8h*)&g_wf[OFH  + lane*8];
    v8h adj[35];
    #pragma unroll
    for (int i = 0; i < 35; ++i)
        adj[i] = *(const v8h*)&g_wf[OFA + i*512 + lane*8];

    // bpermute lane addresses for the P3 rp exchange (loop-invariant)
    const int a_lo  = c << 2;              // lane (0,c)
    const int a_mid = (16 + c) << 2;       // lane (1,c)
    const int a_sel = (q == 3) ? ((32 + c) << 2) : a_lo;   // q3 pulls from (2,c)

    // ---- zero LDS (phantom rows/cols MUST be zero)
    {
        const int4 zz = {0,0,0,0};
        int4* z = (int4*)&sm;
        #pragma unroll 4
        for (int i = lane; i < (int)(sizeof(Smem)/16); i += TPB) z[i] = zz;
    }
    __syncthreads();

    // ---- seed: prop[0]=ann at k=16, bias-one at k=26
    for (int n2 = lane; n2 < NN; n2 += TPB) {
        sm.cat[n2*CATN + 16] = (_Float16)(float)ann_g[blk*NN + n2];
        sm.cat[n2*CATN + 26] = (_Float16)1.0f;
    }
    __syncthreads();

    // ---- P1: ins(prop) -> U   (A=cat rows, B=Wstack frags)
    #define PHASE1() do {                                                        \
        _Pragma("unroll")                                                        \
        for (int mt = 0; mt < 5; ++mt) {                                         \
            const v8h af = *(const v8h*)&sm.cat[(mt*16 + c)*CATN + q*8];         \
            const int node0 = mt*16 + q*4;                                       \
            _Pragma("unroll")                                                    \
            for (int nt = 0; nt < 2; ++nt) {                                     \
                v4f acc = {0.f,0.f,0.f,0.f};                                     \
                acc = __builtin_amdgcn_mfma_f32_16x16x32_f16(                    \
                        af, nt ? w1f1 : w1f0, acc, 0,0,0);                       \
                const int colw = nt*16 + c;                                      \
                if (colw < 30 && node0 <= 68) {                                  \
                    const int e = colw / 10, s = colw - e*10;                    \
                    *(v4h*)&sm.U[s*USTR + e*72 + node0] = pk4(acc);              \
                }                                                                \
            }                                                                    \
        }                                                                        \
    } while(0)

    PHASE1();
    __syncthreads();

    #pragma unroll 1
    for (int step = 0; step < STEPS; ++step) {
        // ---- P2 (operand-swapped): a_in^T = U-frag (A) x adj-frag (B);
        //      adjacency from register-resident adj[] (r4 schedule)
        {
            v8h bfr[7];
            #pragma unroll
            for (int kt = 0; kt < 7; ++kt)
                bfr[kt] = *(const v8h*)&sm.U[c*USTR + q*8 + kt*32];
            #pragma unroll
            for (int mt = 0; mt < 5; ++mt) {
                v4f acc = {0.f,0.f,0.f,0.f};
                #pragma unroll
                for (int kt = 0; kt < 7; ++kt)
                    acc = __builtin_amdgcn_mfma_f32_16x16x32_f16(
                        bfr[kt], adj[mt*7+kt], acc, 0,0,0);
                const int node = mt*16 + c;
                if (node < NN) {
                    const v4h hv = pk4(acc);
                    _Float16* wp = &sm.cat[node*CATN + q*4];   // s = q*4..q*4+3
                    if (q < 2)       *(v4h*)wp = hv;
                    else if (q == 2) *(v2h*)wp = (v2h){hv[0], hv[1]};   // s=8,9
                }
            }
        }
        __syncthreads();   // a_in visible

        // ---- P3 FUSED per node-tile: r,z gates -> rp exchanged via
        //      ds_bpermute (in-register; tiles are row-disjoint so no barrier
        //      or LDS round-trip needed) -> h gate -> state update.
        //      bf2 layout per lane (q,c), row node: k=q*8..q*8+7:
        //        q0: k0-7   = a_in            -> bf unchanged
        //        q1: k8-15  = a_in+zeros      -> bf unchanged
        //        q2: k16-23 = rp s0-7         -> from lanes (0,c),(1,c)
        //        q3: k24,25 = rp s8,9 from (2,c); k26=1; k27-31=0
        {
            #pragma unroll
            for (int nt = 0; nt < 5; ++nt) {
                const int node = nt*16 + c;
                const v8h bf = *(const v8h*)&sm.cat[node*CATN + q*8];
                v4f ar = {0.f,0.f,0.f,0.f}, az = {0.f,0.f,0.f,0.f};
                ar = __builtin_amdgcn_mfma_f32_16x16x32_f16(wrf, bf, ar, 0,0,0);
                az = __builtin_amdgcn_mfma_f32_16x16x32_f16(wzf, bf, az, 0,0,0);
                const v4h pv = *(const v4h*)&sm.cat[node*CATN + 16 + q*4];
                float pg[4], zg[4];
                v4f rpf;
                #pragma unroll
                for (int i = 0; i < 4; ++i) {
                    pg[i]  = (float)pv[i];
                    zg[i]  = fast_sigmoid(az[i]);
                    rpf[i] = fast_sigmoid(ar[i]) * pg[i];
                }
                const v4h rp = pk4(rpf);
                const v2i rpi = __builtin_bit_cast(v2i, rp);
                // cross-lane exchange (4 dwords; q0/q1 results discarded)
                const int d0 = __builtin_amdgcn_ds_bpermute(a_sel, rpi[0]);
                const int d1 = __builtin_amdgcn_ds_bpermute(a_lo,  rpi[1]);
                const int d2 = __builtin_amdgcn_ds_bpermute(a_mid, rpi[0]);
                const int d3 = __builtin_amdgcn_ds_bpermute(a_mid, rpi[1]);
                const v4i bfi = __builtin_bit_cast(v4i, bf);
                v4i b2;
                b2[0] = (q < 2) ? bfi[0] : d0;
                b2[1] = (q < 2) ? bfi[1] : ((q == 2) ? d1 : 0x00003C00); // k26=1
                b2[2] = (q < 2) ? bfi[2] : ((q == 2) ? d2 : 0);
                b2[3] = (q < 2) ? bfi[3] : ((q == 2) ? d3 : 0);
                const v8h bf2 = __builtin_bit_cast(v8h, b2);
                v4f ah = {0.f,0.f,0.f,0.f};
                ah = __builtin_amdgcn_mfma_f32_16x16x32_f16(whf, bf2, ah, 0,0,0);
                v4h pn;
                #pragma unroll
                for (int i = 0; i < 4; ++i) {
                    const float hh = fast_tanh(ah[i]);
                    pn[i] = (_Float16)(pg[i] + zg[i]*(hh - pg[i]));  // RNE state
                }
                if (node < NN) {
                    _Float16* wp = &sm.cat[node*CATN + 16 + q*4];
                    if (q < 2)       *(v4h*)wp = pn;
                    else if (q == 2) *(v2h*)wp = (v2h){pn[0], pn[1]};
                }
            }
        }
        __syncthreads();   // new prop visible (cross-q for P1's reads)

        // ---- P1 for next step
        if (step < STEPS-1) {
            PHASE1();
            __syncthreads();
        }
    }
    #undef PHASE1

    // ---- epilogue: one output per node
    for (int n2 = lane; n2 < NN; n2 += TPB) {
        const _Float16* pc = &sm.cat[n2*CATN + 16];
        const v8h p8 = *(const v8h*)pc;
        const v2h p2 = *(const v2h*)(pc + 8);
        float pr[10];
        #pragma unroll
        for (int i = 0; i < 8; ++i) pr[i] = (float)p8[i];
        pr[8] = (float)p2[0]; pr[9] = (float)p2[1];
        const float av = (float)ann_g[blk*NN + n2];
        float o = gw[PBO2];
        #pragma unroll
        for (int s = 0; s < 10; ++s) {
            const float* wr_ = &gw[PWO1 + s*12];
            float acc = wr_[11] + wr_[10]*av;
            #pragma unroll
            for (int d = 0; d < 10; ++d) acc += pr[d]*wr_[d];
            o += fast_tanh(acc) * gw[PWO2 + s];
        }
        out_g[blk*NN + n2] = (T)o;
    }
}

// __launch_bounds__(64,2): the bound that produced 120-VGPR no-spill codegen
// (r4/r6). Fused P3 drops the zgp/pgp batching arrays -> expect ~105-120 VGPR.
// Tripwire: WRITE_SIZE >> 4.9MB => spill => revert fusion.
__global__ __launch_bounds__(TPB, 2)
void ggnn_kernel(const void* annv, void* outv)
{
    __shared__ Smem sm;
    if (g_flag)
        run_impl<__hip_bfloat16>(annv, outv, sm);
    else
        run_impl<float>(annv, outv, sm);
}

extern "C" void kernel_launch(void* const* d_in, const int* in_sizes, int n_in,
                              void* d_out, int out_size, void* d_ws, size_t ws_size,
                              hipStream_t stream) {
    (void)in_sizes; (void)n_in; (void)out_size; (void)d_ws; (void)ws_size;
    hipLaunchKernelGGL(prep_kernel, dim3(PREPB), dim3(256), 0, stream,
        d_in[0], d_in[1], d_in[2], d_in[3], d_in[4], d_in[5], d_in[6],
        d_in[7], d_in[8], d_in[9], d_in[10], d_in[11], d_in[12], d_in[13]);
    hipLaunchKernelGGL(ggnn_kernel, dim3(NBLK), dim3(TPB), 0, stream,
        d_in[0], d_out);
}